// Round 5
// baseline (4592.232 us; speedup 1.0000x reference)
//
#include <hip/hip_runtime.h>
#include <hip/hip_bf16.h>

#define NT 1024     // tokens per batch
#define DD 384      // embed dim
#define FF 64       // ff dim

typedef __attribute__((ext_vector_type(8))) _Float16 half8;
typedef __attribute__((ext_vector_type(4))) float f32x4;

#define LO_SCALE 2048.f
#define INV2048  4.8828125e-4f   // 1/2048

__device__ __forceinline__ float tanh_fast(float x){
    x = fminf(fmaxf(x, -15.f), 15.f);
    float e = __expf(2.f*x);
    // rcp+mul instead of full-precision div: saves ~6-8 VALU ops, err ~1 ulp
    return (e - 1.f) * __builtin_amdgcn_rcpf(e + 1.f);
}

__device__ __forceinline__ unsigned short h2u(_Float16 h){ return __builtin_bit_cast(unsigned short, h); }

// 2-way fp16 split (Ootomo-Yokota): x ~= hi + lo/2048, hi=RTN fp16, lo=fp16((x-hi)*2048).
// NOTE: hi MUST be RTN (RTZ hi quadruples the residual bound -> absmax blowup).
__device__ __forceinline__ unsigned short split2_comp(float x, int comp){
    _Float16 hi = (_Float16)x;                       // v_cvt_f16_f32 (RTN)
    if (comp == 0) return h2u(hi);
    float r = (x - (float)hi) * LO_SCALE;
    _Float16 lo = (_Float16)r;
    return h2u(lo);
}

// split 4 f32 -> packed half2-as-u32 pairs per component (2 u32 each for hi/lo)
__device__ __forceinline__ void split_pack4(const float* v, unsigned* ph, unsigned* pl){
#pragma unroll
    for (int p=0;p<2;++p){
        float a=v[2*p], b=v[2*p+1];
        _Float16 ha=(_Float16)a, hb=(_Float16)b;     // RTN hi
        ph[p] = (unsigned)h2u(ha) | ((unsigned)h2u(hb)<<16);
        float ra=(a-(float)ha)*LO_SCALE, rb=(b-(float)hb)*LO_SCALE;
        pl[p] = __builtin_bit_cast(unsigned, __builtin_amdgcn_cvt_pkrtz(ra, rb));
    }
}

// ---------------- Prep: fragment-ordered 2-split fp16 weights ----------------
// For W[K][N] row-major: WF[((comp*NMB+mb)*NKB+kb)*512 + l*8 + j]
//   = split2_comp( W[kb*32 + 8*(l>>4) + j][mb*16 + (l&15)], comp )
// W1F: NMB=4,NKB=12 (49152 u16); W2F: NMB=4,NKB=2 (8192); W3F: NMB=24,NKB=2 (49152)
__global__ void k_prep(const float* __restrict__ W1, const float* __restrict__ W2,
                       const float* __restrict__ W3, unsigned short* __restrict__ F)
{
    unsigned short* W1F = F;
    unsigned short* W2F = F + 49152;
    unsigned short* W3F = F + 57344;
    const int t = blockIdx.x*256 + threadIdx.x;
    const int NTH = gridDim.x*256;
    for (int i=t; i<49152; i+=NTH){
        int j=i&7, l=(i>>3)&63, u=i>>9;
        int kb=u%12, v=u/12, mb=v&3, comp=v>>2;
        int k=kb*32+8*(l>>4)+j, c=mb*16+(l&15);
        W1F[i] = split2_comp(W1[k*64+c], comp);
    }
    for (int i=t; i<8192; i+=NTH){
        int j=i&7, l=(i>>3)&63, u=i>>9;
        int kb=u&1, v=u>>1, mb=v&3, comp=v>>2;
        int k=kb*32+8*(l>>4)+j, c=mb*16+(l&15);
        W2F[i] = split2_comp(W2[k*64+c], comp);
    }
    for (int i=t; i<49152; i+=NTH){
        int j=i&7, l=(i>>3)&63, u=i>>9;
        int kb=u&1, v=u>>1, mb=v%24, comp=v/24;
        int k=kb*32+8*(l>>4)+j, c=mb*16+(l&15);
        W3F[i] = split2_comp(W3[k*384+c], comp);
    }
}

// 3 MFMAs per f32-accurate product: HH -> ACC, HL+LH (carry 2048x) -> ACC2.
// Final value = ACC + ACC2 * (1/2048).
#define MFMA3(AH,AL,BH,BL,ACC,ACC2) do{ \
    ACC  = __builtin_amdgcn_mfma_f32_16x16x32_f16(AH,BH,ACC,0,0,0); \
    ACC2 = __builtin_amdgcn_mfma_f32_16x16x32_f16(AH,BL,ACC2,0,0,0); \
    ACC2 = __builtin_amdgcn_mfma_f32_16x16x32_f16(AL,BH,ACC2,0,0,0); \
}while(0)

struct AF { half8 h, l; };
#define LDA(P, CS) AF{ *(const half8*)(P), *(const half8*)((P)+(CS)) }
// LDS fragment tile strides (512-thr): kb stride 2048 u16, lo comp +1024 u16
#define LDB(BASE, KB) do{ \
    bh = *(const half8*)((BASE) + (KB)*2048); \
    bl = *(const half8*)((BASE) + (KB)*2048 + 1024); \
}while(0)

// ---------------- Kernel 1: RK4 ODE + scores (MFMA, 2-split fp16) ----------------
// ROUND-5: R2 structure (512 thr, 32 rows, VGPR-safe at the 128 cap) but with
// h0 state moved from LDS (48.5 KB) into 24 registers -- h0 is per-thread-
// private, it never crosses lanes. LDS drops 114.5 -> 64 KB => 2 INDEPENDENT
// blocks/CU (16 waves, 4/SIMD at the 128-VGPR pool limit). Independent blocks
// overlap each other's barrier drains -- the stall that bounded R2 (true pipe
// util ~20-25%, 3 full-drain barriers per stage with 1 block/CU).
// VGPR headroom paid for by: per-SEC B-fragment loads in M3 (not held across
// all 6 sections), h0l addressing gone, red buffer gone (reuses x1f space).
// accL ping-ponged (accLA/accLB): single accL was a 24-deep dependent-MFMA
// serial chain (~500 cyc/stage floor).
// TRIPWIRE: WRITE_SIZE >> 1 MB means spill; revert/trim next round.
__global__ __launch_bounds__(512) __attribute__((amdgpu_waves_per_eu(4,4)))
void k_ode(const float* __restrict__ emb,
           const float* __restrict__ W1,
           const float* __restrict__ b1, const float* __restrict__ b2,
           const float* __restrict__ b3, const float* __restrict__ Ws,
           const float* __restrict__ bs,
           const unsigned short* __restrict__ W1F,
           const unsigned short* __restrict__ W2F,
           const unsigned short* __restrict__ W3F,
           float* __restrict__ scores)
{
    extern __shared__ char smem[];
    unsigned short* hf  = (unsigned short*)smem;   // [kb12][comp2][nb2][512] u16 = 48 KB
    unsigned short* x1f = hf  + 24576;             // [kb2][comp2][nb2][512] = 8 KB
    unsigned short* x2f = x1f + 4096;              // 8 KB   -> total 64 KB exactly

    unsigned* hf32  = (unsigned*)hf;
    unsigned* x1f32 = (unsigned*)x1f;
    unsigned* x2f32 = (unsigned*)x2f;

    const int tid  = threadIdx.x;
    const int lane = tid & 63;
    const int w    = __builtin_amdgcn_readfirstlane(tid >> 6);
    const int g    = lane >> 4;          // 0..3
    const int rr   = lane & 15;
    const int nb   = w & 1;
    const int mbA  = w >> 1;             // 0..3
    const int rowl = nb*16 + rr;         // 0..31
    const long long row0 = (long long)blockIdx.x * 32;
    const float dt = 0.1f;

    // fragment read bases (u16)
    const unsigned short* hrd  = hf  + nb*512 + lane*8;
    const unsigned short* x1rd = x1f + nb*512 + lane*8;
    const unsigned short* x2rd = x2f + nb*512 + lane*8;
    // fragment write base (u32); kb stride 1024 u32, lo comp at +512 u32
    const unsigned wxp = nb*256 + rr*4 + 2*(g&1);
    const unsigned wx1 = ((unsigned)(mbA>>1))*1024 + 64u*((2*mbA+(g>>1))&3) + wxp;

    // h0 state entirely in registers: 6 t-blocks x 4 = 24 f32, static indexing only
    float h0r[24];
    float arc[24];
#pragma unroll
    for (int t=0;t<6;++t){
        f32x4 v = *(const f32x4*)(emb + (row0+rowl)*DD + mbA*96 + t*16 + 4*g);
        float hw[4] = {v[0],v[1],v[2],v[3]};
#pragma unroll
        for (int r=0;r<4;++r) h0r[4*t+r] = hw[r];
        unsigned ph[2],pl[2];
        split_pack4(hw,ph,pl);
        const unsigned wh = ((unsigned)((6*mbA+t)>>1))*1024 + 64u*((2*t+(g>>1))&3) + wxp;
        *(uint2*)(hf32 + wh       ) = make_uint2(ph[0],ph[1]);
        *(uint2*)(hf32 + wh +  512) = make_uint2(pl[0],pl[1]);
    }

// M3 section: 6 MFMAs for output block t. B frags + b3 acc loaded per-section
// (shrinks cross-section live range). sched_barrier stops cross-section hoisting.
#define M3SEC(T, ACC, ACC2) do{ \
    half8 B0h = *(const half8*)(x2rd); \
    half8 B0l = *(const half8*)(x2rd + 1024); \
    half8 B1h = *(const half8*)(x2rd + 2048); \
    half8 B1l = *(const half8*)(x2rd + 3072); \
    ACC = *(const f32x4*)(b3 + mbA*96 + 16*(T) + 4*g); \
    ACC2 = (f32x4){0.f,0.f,0.f,0.f}; \
    const unsigned short* A3 = W3F + (unsigned)((6*mbA+(T))*2)*512 + lane*8; \
    AF w0 = LDA(A3, 24576); \
    AF w1 = LDA(A3+512, 24576); \
    MFMA3(w0.h,w0.l,B0h,B0l,ACC,ACC2); \
    MFMA3(w1.h,w1.l,B1h,B1l,ACC,ACC2); \
    __builtin_amdgcn_sched_barrier(0); \
}while(0)

// RK4 update for block t: combine hi/lo accs, h0 in regs, accumulate arc,
// write htmp frags
#define M3UPD(T, ACC, ACC2) do{ \
    float hw[4]; \
    if (stage < 3){ \
        _Pragma("unroll") \
        for (int r=0;r<4;++r){ float kr=fmaf(ACC2[r], INV2048, ACC[r]); \
            arc[4*(T)+r] = fmaf(wacc, kr, arc[4*(T)+r]); \
            hw[r] = fmaf(cs, kr, h0r[4*(T)+r]); } \
    } else { \
        _Pragma("unroll") \
        for (int r=0;r<4;++r){ float kr=fmaf(ACC2[r], INV2048, ACC[r]); \
            arc[4*(T)+r] = fmaf(wacc, kr, arc[4*(T)+r]); \
            hw[r] = h0r[4*(T)+r] + arc[4*(T)+r]; \
            h0r[4*(T)+r] = hw[r]; } \
    } \
    unsigned ph[2],pl[2]; \
    split_pack4(hw,ph,pl); \
    const unsigned wh = ((unsigned)((6*mbA+(T))>>1))*1024 + 64u*((2*(T)+(g>>1))&3) + wxp; \
    *(uint2*)(hf32 + wh       ) = make_uint2(ph[0],ph[1]); \
    *(uint2*)(hf32 + wh +  512) = make_uint2(pl[0],pl[1]); \
}while(0)

#pragma unroll 1
    for (int step=0; step<10; ++step){
        const float tstep = dt*(float)step;
#pragma unroll
        for (int j=0;j<24;++j) arc[j]=0.f;

#pragma unroll 1
        for (int stage=0; stage<4; ++stage){
            const float ts = tstep + ((stage==0)?0.f:((stage==3)?dt:0.5f*dt));
            __syncthreads();   // htmp fragments ready

            // ---------- M1^T: x1 = tanh([htmp,t]@W1 + b1) ----------
            // unroll-1 ping-pong: at most 2 A-frag sets (16 regs) in flight;
            // accL ping-ponged too (halves the dependent-MFMA chain on the lo acc)
            f32x4 accA, accB, accLA, accLB;
            {
                f32x4 b1v = *(const f32x4*)(b1 + mbA*16 + 4*g);
                f32x4 wtv = *(const f32x4*)(W1 + 384*64 + mbA*16 + 4*g);
#pragma unroll
                for (int r=0;r<4;++r){ accA[r] = fmaf(ts, wtv[r], b1v[r]); accB[r] = 0.f; accLA[r] = 0.f; accLB[r] = 0.f; }
            }
            {
                const unsigned short* A1 = W1F + mbA*6144 + lane*8;
                AF a0 = LDA(A1, 24576);
#pragma unroll 1
                for (int p=0;p<6;++p){
                    AF a1 = LDA(A1 + (2*p+1)*512, 24576);
                    half8 bh,bl;
                    LDB(hrd, 2*p);
                    MFMA3(a0.h,a0.l,bh,bl,accA,accLA);
                    const int kbn = (p<5) ? (2*p+2) : 0;
                    a0 = LDA(A1 + kbn*512, 24576);
                    LDB(hrd, 2*p+1);
                    MFMA3(a1.h,a1.l,bh,bl,accB,accLB);
                }
            }
            {
                float xv[4];
#pragma unroll
                for (int r=0;r<4;++r) xv[r] = tanh_fast(accA[r] + accB[r] + (accLA[r]+accLB[r])*INV2048);
                unsigned ph[2],pl[2];
                split_pack4(xv,ph,pl);
                *(uint2*)(x1f32 + wx1       ) = make_uint2(ph[0],ph[1]);
                *(uint2*)(x1f32 + wx1 +  512) = make_uint2(pl[0],pl[1]);
            }
            __syncthreads();   // x1 ready

            // ---------- M2^T: x2 = tanh(x1@W2 + b2) ----------
            f32x4 acc2 = *(const f32x4*)(b2 + mbA*16 + 4*g);
            f32x4 acc2L;
            {
#pragma unroll
                for (int r=0;r<4;++r) acc2L[r] = 0.f;
                const unsigned short* A2 = W2F + mbA*1024 + lane*8;
                AF c0 = LDA(A2, 4096);
                AF c1 = LDA(A2 + 512, 4096);
                half8 bh,bl;
                LDB(x1rd, 0);
                MFMA3(c0.h,c0.l,bh,bl,acc2,acc2L);
                LDB(x1rd, 1);
                MFMA3(c1.h,c1.l,bh,bl,acc2,acc2L);
            }
            {
                float xv[4];
#pragma unroll
                for (int r=0;r<4;++r) xv[r] = tanh_fast(acc2[r] + acc2L[r]*INV2048);
                unsigned ph[2],pl[2];
                split_pack4(xv,ph,pl);
                *(uint2*)(x2f32 + wx1       ) = make_uint2(ph[0],ph[1]);
                *(uint2*)(x2f32 + wx1 +  512) = make_uint2(pl[0],pl[1]);
            }
            __syncthreads();   // x2 ready

            // ---------- M3^T + RK4, 6 sections interleaved SEC(t+1) || UPD(t) ----------
            const float wacc = (dt/6.f)*((stage==1||stage==2)?2.f:1.f);
            const float cs   = (stage==2)?dt:0.5f*dt;
            {
                f32x4 ac0,ac1,ac2b,ac3,ac4,ac5;      // hi accs (b3-loaded in SEC)
                f32x4 c0,c1,c2,c3,c4,c5;             // lo accumulators
                M3SEC(0, ac0, c0);
                M3SEC(1, ac1, c1);   M3UPD(0, ac0, c0);
                M3SEC(2, ac2b, c2);  M3UPD(1, ac1, c1);
                M3SEC(3, ac3, c3);   M3UPD(2, ac2b, c2);
                M3SEC(4, ac4, c4);   M3UPD(3, ac3, c3);
                M3SEC(5, ac5, c5);   M3UPD(4, ac4, c4);
                M3UPD(5, ac5, c5);
            }
        } // stage
    } // step

    // ---------- scores = h_final @ Ws + bs ----------
    float part = 0.f;
#pragma unroll
    for (int t=0;t<6;++t){
        f32x4 wsv = *(const f32x4*)(Ws + mbA*96 + t*16 + 4*g);
#pragma unroll
        for (int r=0;r<4;++r) part = fmaf(h0r[4*t+r], wsv[r], part);
    }
    __syncthreads();                       // all LDS matmul reads done
    float* red = (float*)x1f;              // reuse x1f space (2 KB needed)
    red[rowl*16 + mbA*4 + g] = part;
    __syncthreads();
    if (tid < 32){
        float s = bs[0];
#pragma unroll
        for (int q=0;q<16;++q) s += red[tid*16+q];
        scores[row0 + tid] = s;
    }
#undef M3SEC
#undef M3UPD
}

// ---------------- Kernel 2: row_sum[b][i] = sum_j |s_i - s_j| ----------------
__global__ void k_rowsum(const float* __restrict__ scores, float* __restrict__ rs)
{
    __shared__ float s[NT];
    const int b   = blockIdx.x >> 2;
    const int q   = blockIdx.x & 3;
    const int tid = threadIdx.x;
    for (int i=tid; i<NT; i+=256) s[i] = scores[b*NT + i];
    __syncthreads();
    const int i = q*256 + tid;
    const float si = s[i];
    float sum = 0.f;
#pragma unroll 8
    for (int j=0; j<NT; ++j) sum += fabsf(si - s[j]);
    rs[b*NT + i] = sum;
}

// ---------------- Kernel 3: fused softmax(P_max/TAU) @ embeddings ----------------
// Pass-2: 32 lanes x 12 d-cols (stride-32: tx+32u), 4 j per thread — 4 exps/i
// (v_exp quarter-rate). Strided form measured faster than contiguous-float4
// (R10 3.047 vs R14 3.119 ms): better cache-line economy across the wave.
__global__ __launch_bounds__(256, 2)
void k_pv(const float* __restrict__ emb, const float* __restrict__ scores,
          const float* __restrict__ rs, float* __restrict__ out)
{
    __shared__ float s_tt[NT];
    __shared__ float s_rp[NT];
    __shared__ float red_m[8][33];
    __shared__ float red_s[8][33];
    __shared__ float s_M[32], s_I[32];

    const int tid = threadIdx.x;
    const int b   = blockIdx.x >> 5;
    const int j0  = (blockIdx.x & 31) * 32;
    const float invT = 10.f;   // 1/TAU

    for (int i=tid; i<NT; i+=256){
        s_tt[i] =  scores[b*NT + i] * invT;
        s_rp[i] = -rs[b*NT + i] * invT;
    }
    __syncthreads();

    // pass 1: per-j max and exp-sum over i (8 chunks x 32 j)
    {
        const int jl = tid & 31;
        const int ch = tid >> 5;
        const float SC = 1023.f - 2.f*(float)(j0 + jl);
        const int ibeg = ch*128;
        float m = -3.0e38f;
#pragma unroll 4
        for (int i=ibeg; i<ibeg+128; ++i){
            float L = fmaf(s_tt[i], SC, s_rp[i]);
            m = fmaxf(m, L);
        }
        float sum = 0.f;
#pragma unroll 4
        for (int i=ibeg; i<ibeg+128; ++i){
            float L = fmaf(s_tt[i], SC, s_rp[i]);
            sum += __expf(L - m);
        }
        red_m[ch][jl] = m; red_s[ch][jl] = sum;
    }
    __syncthreads();
    if (tid < 32){
        float M = -3.0e38f;
#pragma unroll
        for (int c=0; c<8; ++c) M = fmaxf(M, red_m[c][tid]);
        float S = 0.f;
#pragma unroll
        for (int c=0; c<8; ++c) S += red_s[c][tid]*__expf(red_m[c][tid]-M);
        s_M[tid] = M;
        s_I[tid] = 1.f/S;
    }
    __syncthreads();

    // pass 2: PV accumulate. tx (0..31) -> 12 d-cols (tx+32u), jy (0..7) -> 4 j (jy+8v)
    const int tx = tid & 31;
    const int jy = tid >> 5;
    float accv[4][12];
#pragma unroll
    for (int v=0; v<4; ++v)
#pragma unroll
        for (int u=0; u<12; ++u) accv[v][u] = 0.f;

    float SCv[4], Mv[4], Iv[4];
#pragma unroll
    for (int v=0; v<4; ++v){
        const int jl = jy + 8*v;
        SCv[v] = 1023.f - 2.f*(float)(j0 + jl);
        Mv[v]  = s_M[jl];
        Iv[v]  = s_I[jl];
    }
    const float* ep = emb + ((long long)b*NT)*DD + tx;
#pragma unroll 2
    for (int i=0; i<NT; ++i){
        const float ti = s_tt[i], ri = s_rp[i];
        float ev[12];
#pragma unroll
        for (int u=0; u<12; ++u) ev[u] = ep[(long long)i*DD + 32*u];
        float p[4];
#pragma unroll
        for (int v=0; v<4; ++v)
            p[v] = __expf(fmaf(ti, SCv[v], ri) - Mv[v]);
#pragma unroll
        for (int v=0; v<4; ++v)
#pragma unroll
            for (int u=0; u<12; ++u) accv[v][u] = fmaf(p[v], ev[u], accv[v][u]);
    }
#pragma unroll
    for (int v=0; v<4; ++v){
        float* op = out + ((long long)b*NT + j0 + jy + 8*v)*DD + tx;
#pragma unroll
        for (int u=0; u<12; ++u) op[32*u] = accv[v][u]*Iv[v];
    }
}

extern "C" void kernel_launch(void* const* d_in, const int* in_sizes, int n_in,
                              void* d_out, int out_size, void* d_ws, size_t ws_size,
                              hipStream_t stream)
{
    const float* emb = (const float*)d_in[0];
    const float* W1  = (const float*)d_in[1];
    const float* b1  = (const float*)d_in[2];
    const float* W2  = (const float*)d_in[3];
    const float* b2  = (const float*)d_in[4];
    const float* W3  = (const float*)d_in[5];
    const float* b3  = (const float*)d_in[6];
    const float* Ws  = (const float*)d_in[7];
    const float* bs  = (const float*)d_in[8];

    const int B = in_sizes[0] / (NT*DD);
    float* out    = (float*)d_out;
    float* scores = out + (long long)B*NT*DD;   // scores tail of output

    unsigned short* WF = (unsigned short*)d_ws;     // W1F | W2F | W3F (fp16 2-split)
    const unsigned short* W1F = WF;
    const unsigned short* W2F = WF + 49152;
    const unsigned short* W3F = WF + 57344;
    float* rsum = (float*)((char*)d_ws + 319488);   // B*NT floats (offset kept from prior rounds)

    const int ODE_LDS = 65536;   // 64 KB dynamic LDS -> 2 blocks/CU
    hipFuncSetAttribute(reinterpret_cast<const void*>(k_ode),
                        hipFuncAttributeMaxDynamicSharedMemorySize, ODE_LDS);

    hipLaunchKernelGGL(k_prep, dim3(64), dim3(256), 0, stream, W1, W2, W3, WF);
    hipLaunchKernelGGL(k_ode, dim3(B*NT/32), dim3(512), ODE_LDS, stream,
                       emb, W1, b1, b2, b3, Ws, bs, W1F, W2F, W3F, scores);
    hipLaunchKernelGGL(k_rowsum, dim3(B*4), dim3(256), 0, stream, scores, rsum);
    hipLaunchKernelGGL(k_pv, dim3(B*32), dim3(256), 0, stream, emb, scores, rsum, out);
}

// Round 6
// 2082.893 us; speedup vs baseline: 2.2047x; 2.2047x over previous
//
#include <hip/hip_runtime.h>
#include <hip/hip_bf16.h>

#define NT 1024     // tokens per batch
#define DD 384      // embed dim
#define FF 64       // ff dim

typedef __attribute__((ext_vector_type(8))) _Float16 half8;
typedef __attribute__((ext_vector_type(4))) float f32x4;

#define LO_SCALE 2048.f
#define INV2048  4.8828125e-4f   // 1/2048

__device__ __forceinline__ float tanh_fast(float x){
    x = fminf(fmaxf(x, -15.f), 15.f);
    float e = __expf(2.f*x);
    // rcp+mul instead of div: saves ~6-8 VALU ops, err ~1 ulp
    return (e - 1.f) * __builtin_amdgcn_rcpf(e + 1.f);
}

__device__ __forceinline__ unsigned short h2u(_Float16 h){ return __builtin_bit_cast(unsigned short, h); }

// 2-way fp16 split (Ootomo-Yokota): x ~= hi + lo/2048, hi=RTN fp16, lo=fp16((x-hi)*2048).
// NOTE: hi MUST be RTN (RTZ hi quadruples the residual bound -> absmax blowup).
__device__ __forceinline__ unsigned short split2_comp(float x, int comp){
    _Float16 hi = (_Float16)x;                       // v_cvt_f16_f32 (RTN)
    if (comp == 0) return h2u(hi);
    float r = (x - (float)hi) * LO_SCALE;
    _Float16 lo = (_Float16)r;
    return h2u(lo);
}

// split 4 f32 -> packed half2-as-u32 pairs per component (2 u32 each for hi/lo)
__device__ __forceinline__ void split_pack4(const float* v, unsigned* ph, unsigned* pl){
#pragma unroll
    for (int p=0;p<2;++p){
        float a=v[2*p], b=v[2*p+1];
        _Float16 ha=(_Float16)a, hb=(_Float16)b;     // RTN hi
        ph[p] = (unsigned)h2u(ha) | ((unsigned)h2u(hb)<<16);
        float ra=(a-(float)ha)*LO_SCALE, rb=(b-(float)hb)*LO_SCALE;
        pl[p] = __builtin_bit_cast(unsigned, __builtin_amdgcn_cvt_pkrtz(ra, rb));
    }
}

// ---------------- Prep: fragment-ordered 2-split fp16 weights ----------------
// For W[K][N] row-major: WF[((comp*NMB+mb)*NKB+kb)*512 + l*8 + j]
//   = split2_comp( W[kb*32 + 8*(l>>4) + j][mb*16 + (l&15)], comp )
// W1F: NMB=4,NKB=12 (49152 u16); W2F: NMB=4,NKB=2 (8192); W3F: NMB=24,NKB=2 (49152)
__global__ void k_prep(const float* __restrict__ W1, const float* __restrict__ W2,
                       const float* __restrict__ W3, unsigned short* __restrict__ F)
{
    unsigned short* W1F = F;
    unsigned short* W2F = F + 49152;
    unsigned short* W3F = F + 57344;
    const int t = blockIdx.x*256 + threadIdx.x;
    const int NTH = gridDim.x*256;
    for (int i=t; i<49152; i+=NTH){
        int j=i&7, l=(i>>3)&63, u=i>>9;
        int kb=u%12, v=u/12, mb=v&3, comp=v>>2;
        int k=kb*32+8*(l>>4)+j, c=mb*16+(l&15);
        W1F[i] = split2_comp(W1[k*64+c], comp);
    }
    for (int i=t; i<8192; i+=NTH){
        int j=i&7, l=(i>>3)&63, u=i>>9;
        int kb=u&1, v=u>>1, mb=v&3, comp=v>>2;
        int k=kb*32+8*(l>>4)+j, c=mb*16+(l&15);
        W2F[i] = split2_comp(W2[k*64+c], comp);
    }
    for (int i=t; i<49152; i+=NTH){
        int j=i&7, l=(i>>3)&63, u=i>>9;
        int kb=u&1, v=u>>1, mb=v%24, comp=v/24;
        int k=kb*32+8*(l>>4)+j, c=mb*16+(l&15);
        W3F[i] = split2_comp(W3[k*384+c], comp);
    }
}

// 3 MFMAs per f32-accurate product: HH -> ACC, HL+LH (carry 2048x) -> ACC2.
// Final value = ACC + ACC2 * (1/2048).
#define MFMA3(AH,AL,BH,BL,ACC,ACC2) do{ \
    ACC  = __builtin_amdgcn_mfma_f32_16x16x32_f16(AH,BH,ACC,0,0,0); \
    ACC2 = __builtin_amdgcn_mfma_f32_16x16x32_f16(AH,BL,ACC2,0,0,0); \
    ACC2 = __builtin_amdgcn_mfma_f32_16x16x32_f16(AL,BH,ACC2,0,0,0); \
}while(0)

struct AF { half8 h, l; };
#define LDA(P, CS) AF{ *(const half8*)(P), *(const half8*)((P)+(CS)) }
#define LDB(BASE, KB) do{ \
    bh = *(const half8*)((BASE) + (KB)*2048); \
    bl = *(const half8*)((BASE) + (KB)*2048 + 1024); \
}while(0)

// ---------------- Kernel 1: RK4 ODE + scores (MFMA, 2-split fp16) ----------------
// ROUND-6: revert to the verified R2 operating point (512 thr, waves_per_eu(2,2),
// VGPR 120 <= the immovable 128 cap, 114.5 KB LDS, 1 block/CU) — R3/R4/R5 proved
// every occupancy knob (waves_per_eu 3 / 3,3 / 4,4; 256-thr blocks) only drives
// the VGPR cap DOWN (84/64) and spills catastrophically. On top of R2, three
// allocator-safe micro-opts (+~12 VGPR, inside R2's slack):
//   1. rcp-based tanh (-6 VALU x 8/stage)
//   2. accLA/accLB ping-pong: single accL was a 12-deep dependent-MFMA chain in M1
//   3. M1 B-fragment ping-pong: ds_read_b128 issued one MFMA3-group (~60cyc) ahead
// TRIPWIRE: WRITE_SIZE >> 0.3 MB means the +12 regs spilled; strip opt 3 next.
__global__ __launch_bounds__(512) __attribute__((amdgpu_waves_per_eu(2,2)))
void k_ode(const float* __restrict__ emb,
           const float* __restrict__ W1,
           const float* __restrict__ b1, const float* __restrict__ b2,
           const float* __restrict__ b3, const float* __restrict__ Ws,
           const float* __restrict__ bs,
           const unsigned short* __restrict__ W1F,
           const unsigned short* __restrict__ W2F,
           const unsigned short* __restrict__ W3F,
           float* __restrict__ scores)
{
    extern __shared__ char smem[];
    unsigned short* hf  = (unsigned short*)smem;   // [kb12][comp2][nb2][512] u16 = 48 KB
    unsigned short* x1f = hf  + 24576;             // 8 KB
    unsigned short* x2f = x1f + 4096;              // 8 KB
    float*          red = (float*)(x2f + 4096);    // 2 KB  @65536
    float*          h0l = red + 512;               // [32][388] f32 = 48.5 KB @67584

    unsigned* hf32  = (unsigned*)hf;
    unsigned* x1f32 = (unsigned*)x1f;
    unsigned* x2f32 = (unsigned*)x2f;

    const int tid  = threadIdx.x;
    const int lane = tid & 63;
    const int w    = __builtin_amdgcn_readfirstlane(tid >> 6);
    const int g    = lane >> 4;          // 0..3
    const int rr   = lane & 15;
    const int nb   = w & 1;
    const int mbA  = w >> 1;             // 0..3
    const int rowl = nb*16 + rr;         // 0..31
    const long long row0 = (long long)blockIdx.x * 32;
    const float dt = 0.1f;

    // fragment read bases (u16)
    const unsigned short* hrd  = hf  + nb*512 + lane*8;
    const unsigned short* x1rd = x1f + nb*512 + lane*8;
    const unsigned short* x2rd = x2f + nb*512 + lane*8;
    // fragment write base (u32); kb stride 1024 u32, lo comp at +512 u32
    const unsigned wxp = nb*256 + rr*4 + 2*(g&1);
    const unsigned wx1 = ((unsigned)(mbA>>1))*1024 + 64u*((2*mbA+(g>>1))&3) + wxp;
    // h0 LDS base (f32, stride 388 per row)
    const int h0base = rowl*388 + mbA*96 + 4*g;

    // state init: h0 -> LDS, htmp fragments -> LDS; arc stays in registers
    float arc[24];
#pragma unroll
    for (int t=0;t<6;++t){
        f32x4 v = *(const f32x4*)(emb + (row0+rowl)*DD + mbA*96 + t*16 + 4*g);
        float hw[4] = {v[0],v[1],v[2],v[3]};
        *(float4*)(h0l + h0base + 16*t) = make_float4(hw[0],hw[1],hw[2],hw[3]);
        unsigned ph[2],pl[2];
        split_pack4(hw,ph,pl);
        const unsigned wh = ((unsigned)((6*mbA+t)>>1))*1024 + 64u*((2*t+(g>>1))&3) + wxp;
        *(uint2*)(hf32 + wh       ) = make_uint2(ph[0],ph[1]);
        *(uint2*)(hf32 + wh +  512) = make_uint2(pl[0],pl[1]);
    }

// M3 section: 6 MFMAs for output block t; sched_barrier stops cross-section hoisting
#define M3SEC(T, ACC, ACC2) do{ \
    ACC2 = (f32x4){0.f,0.f,0.f,0.f}; \
    const unsigned short* A3 = W3F + (unsigned)((6*mbA+(T))*2)*512 + lane*8; \
    AF w0 = LDA(A3, 24576); \
    AF w1 = LDA(A3+512, 24576); \
    MFMA3(w0.h,w0.l,B0h,B0l,ACC,ACC2); \
    MFMA3(w1.h,w1.l,B1h,B1l,ACC,ACC2); \
    __builtin_amdgcn_sched_barrier(0); \
}while(0)

// RK4 update for block t: combine hi/lo accs, read h0 from LDS, accumulate arc,
// write htmp frags
#define M3UPD(T, ACC, ACC2) do{ \
    f32x4 h0v = *(const f32x4*)(h0l + h0base + 16*(T)); \
    float hw[4]; \
    if (stage < 3){ \
        _Pragma("unroll") \
        for (int r=0;r<4;++r){ float kr=fmaf(ACC2[r], INV2048, ACC[r]); \
            arc[4*(T)+r] = fmaf(wacc, kr, arc[4*(T)+r]); \
            hw[r] = fmaf(cs, kr, h0v[r]); } \
    } else { \
        _Pragma("unroll") \
        for (int r=0;r<4;++r){ float kr=fmaf(ACC2[r], INV2048, ACC[r]); \
            arc[4*(T)+r] = fmaf(wacc, kr, arc[4*(T)+r]); \
            hw[r] = h0v[r] + arc[4*(T)+r]; } \
        *(float4*)(h0l + h0base + 16*(T)) = make_float4(hw[0],hw[1],hw[2],hw[3]); \
    } \
    unsigned ph[2],pl[2]; \
    split_pack4(hw,ph,pl); \
    const unsigned wh = ((unsigned)((6*mbA+(T))>>1))*1024 + 64u*((2*(T)+(g>>1))&3) + wxp; \
    *(uint2*)(hf32 + wh       ) = make_uint2(ph[0],ph[1]); \
    *(uint2*)(hf32 + wh +  512) = make_uint2(pl[0],pl[1]); \
}while(0)

#pragma unroll 1
    for (int step=0; step<10; ++step){
        const float tstep = dt*(float)step;
#pragma unroll
        for (int j=0;j<24;++j) arc[j]=0.f;

#pragma unroll 1
        for (int stage=0; stage<4; ++stage){
            const float ts = tstep + ((stage==0)?0.f:((stage==3)?dt:0.5f*dt));
            __syncthreads();   // htmp fragments ready

            // ---------- M1^T: x1 = tanh([htmp,t]@W1 + b1) ----------
            // A-frag ping-pong (global) + B-frag ping-pong (LDS): each ds_read
            // issued one MFMA3-group ahead of use. accL split halves dep chain.
            f32x4 accA, accB, accLA, accLB;
            {
                f32x4 b1v = *(const f32x4*)(b1 + mbA*16 + 4*g);
                f32x4 wtv = *(const f32x4*)(W1 + 384*64 + mbA*16 + 4*g);
#pragma unroll
                for (int r=0;r<4;++r){ accA[r] = fmaf(ts, wtv[r], b1v[r]); accB[r] = 0.f; accLA[r] = 0.f; accLB[r] = 0.f; }
            }
            {
                const unsigned short* A1 = W1F + mbA*6144 + lane*8;
                AF a0 = LDA(A1, 24576);
                half8 bh0 = *(const half8*)(hrd);
                half8 bl0 = *(const half8*)(hrd + 1024);
#pragma unroll 1
                for (int p=0;p<6;++p){
                    AF a1 = LDA(A1 + (2*p+1)*512, 24576);
                    half8 bh1 = *(const half8*)(hrd + (2*p+1)*2048);
                    half8 bl1 = *(const half8*)(hrd + (2*p+1)*2048 + 1024);
                    MFMA3(a0.h,a0.l,bh0,bl0,accA,accLA);
                    const int kbn = (p<5) ? (2*p+2) : 0;
                    a0 = LDA(A1 + kbn*512, 24576);
                    bh0 = *(const half8*)(hrd + kbn*2048);
                    bl0 = *(const half8*)(hrd + kbn*2048 + 1024);
                    MFMA3(a1.h,a1.l,bh1,bl1,accB,accLB);
                }
            }
            {
                float xv[4];
#pragma unroll
                for (int r=0;r<4;++r) xv[r] = tanh_fast(accA[r] + accB[r] + (accLA[r]+accLB[r])*INV2048);
                unsigned ph[2],pl[2];
                split_pack4(xv,ph,pl);
                *(uint2*)(x1f32 + wx1       ) = make_uint2(ph[0],ph[1]);
                *(uint2*)(x1f32 + wx1 +  512) = make_uint2(pl[0],pl[1]);
            }
            __syncthreads();   // x1 ready

            // ---------- M2^T: x2 = tanh(x1@W2 + b2) ----------
            f32x4 acc2 = *(const f32x4*)(b2 + mbA*16 + 4*g);
            f32x4 acc2L;
            {
#pragma unroll
                for (int r=0;r<4;++r) acc2L[r] = 0.f;
                const unsigned short* A2 = W2F + mbA*1024 + lane*8;
                AF c0 = LDA(A2, 4096);
                AF c1 = LDA(A2 + 512, 4096);
                half8 bh,bl;
                LDB(x1rd, 0);
                MFMA3(c0.h,c0.l,bh,bl,acc2,acc2L);
                LDB(x1rd, 1);
                MFMA3(c1.h,c1.l,bh,bl,acc2,acc2L);
            }
            {
                float xv[4];
#pragma unroll
                for (int r=0;r<4;++r) xv[r] = tanh_fast(acc2[r] + acc2L[r]*INV2048);
                unsigned ph[2],pl[2];
                split_pack4(xv,ph,pl);
                *(uint2*)(x2f32 + wx1       ) = make_uint2(ph[0],ph[1]);
                *(uint2*)(x2f32 + wx1 +  512) = make_uint2(pl[0],pl[1]);
            }
            __syncthreads();   // x2 ready

            // ---------- M3^T + RK4, 6 sections interleaved SEC(t+1) || UPD(t) ----------
            const float wacc = (dt/6.f)*((stage==1||stage==2)?2.f:1.f);
            const float cs   = (stage==2)?dt:0.5f*dt;
            {
                half8 B0h = *(const half8*)(x2rd);
                half8 B0l = *(const half8*)(x2rd + 1024);
                half8 B1h = *(const half8*)(x2rd + 2048);
                half8 B1l = *(const half8*)(x2rd + 3072);
                f32x4 ac0 = *(const f32x4*)(b3 + mbA*96       + 4*g);
                f32x4 ac1 = *(const f32x4*)(b3 + mbA*96 + 16  + 4*g);
                f32x4 ac2b = *(const f32x4*)(b3 + mbA*96 + 32 + 4*g);
                f32x4 ac3 = *(const f32x4*)(b3 + mbA*96 + 48  + 4*g);
                f32x4 ac4 = *(const f32x4*)(b3 + mbA*96 + 64  + 4*g);
                f32x4 ac5 = *(const f32x4*)(b3 + mbA*96 + 80  + 4*g);
                f32x4 c0,c1,c2,c3,c4,c5;   // lo accumulators (zeroed in M3SEC)
                M3SEC(0, ac0, c0);
                M3SEC(1, ac1, c1);   M3UPD(0, ac0, c0);
                M3SEC(2, ac2b, c2);  M3UPD(1, ac1, c1);
                M3SEC(3, ac3, c3);   M3UPD(2, ac2b, c2);
                M3SEC(4, ac4, c4);   M3UPD(3, ac3, c3);
                M3SEC(5, ac5, c5);   M3UPD(4, ac4, c4);
                M3UPD(5, ac5, c5);
            }
        } // stage
    } // step

    // ---------- scores = h_final @ Ws + bs ----------
    float part = 0.f;
#pragma unroll
    for (int t=0;t<6;++t){
        f32x4 hv  = *(const f32x4*)(h0l + h0base + 16*t);
        f32x4 wsv = *(const f32x4*)(Ws + mbA*96 + t*16 + 4*g);
#pragma unroll
        for (int r=0;r<4;++r) part = fmaf(hv[r], wsv[r], part);
    }
    __syncthreads();
    red[rowl*16 + mbA*4 + g] = part;
    __syncthreads();
    if (tid < 32){
        float s = bs[0];
#pragma unroll
        for (int q=0;q<16;++q) s += red[tid*16+q];
        scores[row0 + tid] = s;
    }
#undef M3SEC
#undef M3UPD
}

// ---------------- Kernel 2: row_sum[b][i] = sum_j |s_i - s_j| ----------------
__global__ void k_rowsum(const float* __restrict__ scores, float* __restrict__ rs)
{
    __shared__ float s[NT];
    const int b   = blockIdx.x >> 2;
    const int q   = blockIdx.x & 3;
    const int tid = threadIdx.x;
    for (int i=tid; i<NT; i+=256) s[i] = scores[b*NT + i];
    __syncthreads();
    const int i = q*256 + tid;
    const float si = s[i];
    float sum = 0.f;
#pragma unroll 8
    for (int j=0; j<NT; ++j) sum += fabsf(si - s[j]);
    rs[b*NT + i] = sum;
}

// ---------------- Kernel 3: fused softmax(P_max/TAU) @ embeddings ----------------
// Pass-2: 32 lanes x 12 d-cols (stride-32: tx+32u), 4 j per thread — 4 exps/i
// (v_exp quarter-rate). Strided form measured faster than contiguous-float4
// (R10 3.047 vs R14 3.119 ms): better cache-line economy across the wave.
__global__ __launch_bounds__(256, 2)
void k_pv(const float* __restrict__ emb, const float* __restrict__ scores,
          const float* __restrict__ rs, float* __restrict__ out)
{
    __shared__ float s_tt[NT];
    __shared__ float s_rp[NT];
    __shared__ float red_m[8][33];
    __shared__ float red_s[8][33];
    __shared__ float s_M[32], s_I[32];

    const int tid = threadIdx.x;
    const int b   = blockIdx.x >> 5;
    const int j0  = (blockIdx.x & 31) * 32;
    const float invT = 10.f;   // 1/TAU

    for (int i=tid; i<NT; i+=256){
        s_tt[i] =  scores[b*NT + i] * invT;
        s_rp[i] = -rs[b*NT + i] * invT;
    }
    __syncthreads();

    // pass 1: per-j max and exp-sum over i (8 chunks x 32 j)
    {
        const int jl = tid & 31;
        const int ch = tid >> 5;
        const float SC = 1023.f - 2.f*(float)(j0 + jl);
        const int ibeg = ch*128;
        float m = -3.0e38f;
#pragma unroll 4
        for (int i=ibeg; i<ibeg+128; ++i){
            float L = fmaf(s_tt[i], SC, s_rp[i]);
            m = fmaxf(m, L);
        }
        float sum = 0.f;
#pragma unroll 4
        for (int i=ibeg; i<ibeg+128; ++i){
            float L = fmaf(s_tt[i], SC, s_rp[i]);
            sum += __expf(L - m);
        }
        red_m[ch][jl] = m; red_s[ch][jl] = sum;
    }
    __syncthreads();
    if (tid < 32){
        float M = -3.0e38f;
#pragma unroll
        for (int c=0; c<8; ++c) M = fmaxf(M, red_m[c][tid]);
        float S = 0.f;
#pragma unroll
        for (int c=0; c<8; ++c) S += red_s[c][tid]*__expf(red_m[c][tid]-M);
        s_M[tid] = M;
        s_I[tid] = 1.f/S;
    }
    __syncthreads();

    // pass 2: PV accumulate. tx (0..31) -> 12 d-cols (tx+32u), jy (0..7) -> 4 j (jy+8v)
    const int tx = tid & 31;
    const int jy = tid >> 5;
    float accv[4][12];
#pragma unroll
    for (int v=0; v<4; ++v)
#pragma unroll
        for (int u=0; u<12; ++u) accv[v][u] = 0.f;

    float SCv[4], Mv[4], Iv[4];
#pragma unroll
    for (int v=0; v<4; ++v){
        const int jl = jy + 8*v;
        SCv[v] = 1023.f - 2.f*(float)(j0 + jl);
        Mv[v]  = s_M[jl];
        Iv[v]  = s_I[jl];
    }
    const float* ep = emb + ((long long)b*NT)*DD + tx;
#pragma unroll 2
    for (int i=0; i<NT; ++i){
        const float ti = s_tt[i], ri = s_rp[i];
        float ev[12];
#pragma unroll
        for (int u=0; u<12; ++u) ev[u] = ep[(long long)i*DD + 32*u];
        float p[4];
#pragma unroll
        for (int v=0; v<4; ++v)
            p[v] = __expf(fmaf(ti, SCv[v], ri) - Mv[v]);
#pragma unroll
        for (int v=0; v<4; ++v)
#pragma unroll
            for (int u=0; u<12; ++u) accv[v][u] = fmaf(p[v], ev[u], accv[v][u]);
    }
#pragma unroll
    for (int v=0; v<4; ++v){
        float* op = out + ((long long)b*NT + j0 + jy + 8*v)*DD + tx;
#pragma unroll
        for (int u=0; u<12; ++u) op[32*u] = accv[v][u]*Iv[v];
    }
}

extern "C" void kernel_launch(void* const* d_in, const int* in_sizes, int n_in,
                              void* d_out, int out_size, void* d_ws, size_t ws_size,
                              hipStream_t stream)
{
    const float* emb = (const float*)d_in[0];
    const float* W1  = (const float*)d_in[1];
    const float* b1  = (const float*)d_in[2];
    const float* W2  = (const float*)d_in[3];
    const float* b2  = (const float*)d_in[4];
    const float* W3  = (const float*)d_in[5];
    const float* b3  = (const float*)d_in[6];
    const float* Ws  = (const float*)d_in[7];
    const float* bs  = (const float*)d_in[8];

    const int B = in_sizes[0] / (NT*DD);
    float* out    = (float*)d_out;
    float* scores = out + (long long)B*NT*DD;   // scores tail of output

    unsigned short* WF = (unsigned short*)d_ws;     // W1F | W2F | W3F (fp16 2-split)
    const unsigned short* W1F = WF;
    const unsigned short* W2F = WF + 49152;
    const unsigned short* W3F = WF + 57344;
    float* rsum = (float*)((char*)d_ws + 319488);   // B*NT floats (offset kept from prior rounds)

    const int ODE_LDS = 117248;   // 114.5 KB dynamic LDS, 1 block/CU
    hipFuncSetAttribute(reinterpret_cast<const void*>(k_ode),
                        hipFuncAttributeMaxDynamicSharedMemorySize, ODE_LDS);

    hipLaunchKernelGGL(k_prep, dim3(64), dim3(256), 0, stream, W1, W2, W3, WF);
    hipLaunchKernelGGL(k_ode, dim3(B*NT/32), dim3(512), ODE_LDS, stream,
                       emb, W1, b1, b2, b3, Ws, bs, W1F, W2F, W3F, scores);
    hipLaunchKernelGGL(k_rowsum, dim3(B*4), dim3(256), 0, stream, scores, rsum);
    hipLaunchKernelGGL(k_pv, dim3(B*32), dim3(256), 0, stream, emb, scores, rsum, out);
}